// Round 1
// baseline (748.987 us; speedup 1.0000x reference)
//
#include <hip/hip_runtime.h>
#include <math.h>

namespace {
constexpr int K = 16, T = 8, R = 8, NB = 32;      // freqs, tx, rx, batch
constexpr int NX = 64, NY = 64, NZ = 32;
constexpr int NVOX = NX * NY * NZ;                 // 131072
constexpr int KTRN = K * T * R * NB;               // 32768
// 2*pi / c
constexpr float TWO_PI_OVER_C = (float)(6.283185307179586 / 299792458.0);
}

// ---------------------------------------------------------------------------
// Prep: zero the max slot; transpose y_real/y_imag (N,K,T,R) -> yt[t][r][k][n][2]
// so each (t,r) chunk is 16*32*2 = 1024 contiguous floats (4 KB).
// ---------------------------------------------------------------------------
__global__ void prep_kernel(const float* __restrict__ yr, const float* __restrict__ yi,
                            float* __restrict__ yt, unsigned int* __restrict__ maxslot,
                            int use_yt) {
    int idx = blockIdx.x * blockDim.x + threadIdx.x;
    if (idx == 0) *maxslot = 0u;
    if (use_yt && idx < KTRN) {
        int n = idx & (NB - 1);          // bits [0,5)
        int r = (idx >> 5) & (R - 1);    // bits [5,8)
        int t = (idx >> 8) & (T - 1);    // bits [8,11)
        int k = idx >> 11;               // bits [11,15)
        int src = ((n * K + k) * T + t) * R + r;
        int dst = (((t * R + r) * K + k) * NB + n) * 2;
        yt[dst]     = yr[src];
        yt[dst + 1] = yi[src];
    }
}

// ---------------------------------------------------------------------------
// Main: 1 thread = 1 voxel, 32 complex accumulators in registers.
// ---------------------------------------------------------------------------
__global__ __launch_bounds__(256, 2) void kirchhoff_main(
    const float* __restrict__ freqs,
    const float* __restrict__ txp, const float* __restrict__ rxp,
    const float* __restrict__ xcrd, const float* __restrict__ ycrd, const float* __restrict__ zcrd,
    const float* __restrict__ yt,   // transposed y (valid if use_yt)
    const float* __restrict__ yr, const float* __restrict__ yi,  // fallback
    float* __restrict__ out, unsigned int* __restrict__ maxslot, int use_yt)
{
    __shared__ __align__(16) float s_y[K * NB * 2];   // 4 KB per (t,r) chunk
    __shared__ float s_ks[K];
    __shared__ float s_wmax[4];

    const int tid = threadIdx.x;
    const int v = blockIdx.x * 256 + tid;
    const int iz = v & (NZ - 1);
    const int iy = (v >> 5) & (NY - 1);
    const int ix = v >> 11;

    const float px = xcrd[ix];
    const float py = ycrd[iy];
    const float pz = zcrd[iz];

    if (tid < K) s_ks[tid] = TWO_PI_OVER_C * freqs[tid];

    float accRe[NB], accIm[NB];
#pragma unroll
    for (int n = 0; n < NB; ++n) { accRe[n] = 0.0f; accIm[n] = 0.0f; }

    for (int tr = 0; tr < T * R; ++tr) {
        const int t  = tr >> 3;
        const int ir = tr & 7;

        // ---- stage this (t,r)'s y chunk into LDS ----
        __syncthreads();   // previous iteration's readers done (also publishes s_ks)
        if (use_yt) {
            const float4* src4 = (const float4*)(yt + tr * (K * NB * 2));
            ((float4*)s_y)[tid] = src4[tid];
        } else {
#pragma unroll
            for (int j = 0; j < 2; ++j) {
                int p = tid + j * 256;          // 512 (k,n) pairs
                int kk = p >> 5, n = p & 31;
                int src = ((n * K + kk) * T + t) * R + ir;
                s_y[(kk * NB + n) * 2]     = yr[src];
                s_y[(kk * NB + n) * 2 + 1] = yi[src];
            }
        }
        __syncthreads();

        // ---- per-(t,r) geometry (uniform tx/rx loads; per-lane voxel math) ----
        const float tx0 = txp[t * 3 + 0], tx1 = txp[t * 3 + 1], tx2 = txp[t * 3 + 2];
        const float rx0 = rxp[ir * 3 + 0], rx1 = rxp[ir * 3 + 1], rx2 = rxp[ir * 3 + 2];
        float dxt = px - tx0, dyt = py - tx1, dzt = pz - tx2;
        float dxr = px - rx0, dyr = py - rx1, dzr = pz - rx2;
        float Rt = sqrtf(dxt * dxt + dyt * dyt + dzt * dzt);
        float Rr = sqrtf(dxr * dxr + dyr * dyr + dzr * dzr);
        float Rsum  = Rt + Rr;
        float Rprod = Rt * Rr;
        float g = 4.0f * dzt * dzr * __builtin_amdgcn_rcpf(Rprod);
        float gRsum = g * Rsum;

#pragma unroll 2
        for (int k = 0; k < K; ++k) {
            float kk = s_ks[k];
            float phase = kk * Rsum;
            float c1  = fmaf(-(kk * kk), Rprod, 1.0f);
            float gc1 = g * c1;
            float gph = kk * gRsum;
            float sv, cv;
            __sincosf(phase, &sv, &cv);
            float Are = fmaf(gc1, cv, -gph * sv);
            float Aim = fmaf(gc1, sv,  gph * cv);

            const float4* yk4 = (const float4*)(s_y + k * (NB * 2));
#pragma unroll
            for (int n2 = 0; n2 < NB / 2; ++n2) {
                float4 yv = yk4[n2];   // (re0, im0, re1, im1) — broadcast ds_read_b128
                int n = n2 * 2;
                accRe[n]     = fmaf(Are, yv.x, fmaf(-Aim, yv.y, accRe[n]));
                accIm[n]     = fmaf(Are, yv.y, fmaf( Aim, yv.x, accIm[n]));
                accRe[n + 1] = fmaf(Are, yv.z, fmaf(-Aim, yv.w, accRe[n + 1]));
                accIm[n + 1] = fmaf(Are, yv.w, fmaf( Aim, yv.z, accIm[n + 1]));
            }
        }
    }

    // ---- magnitudes, store, block max -> global atomicMax ----
    float m = 0.0f;
#pragma unroll
    for (int n = 0; n < NB; ++n) {
        float mag = sqrtf(accRe[n] * accRe[n] + accIm[n] * accIm[n]);
        out[n * NVOX + v] = mag;
        m = fmaxf(m, mag);
    }
#pragma unroll
    for (int off = 32; off > 0; off >>= 1)
        m = fmaxf(m, __shfl_down(m, off));
    if ((tid & 63) == 0) s_wmax[tid >> 6] = m;
    __syncthreads();
    if (tid == 0) {
        float bm = fmaxf(fmaxf(s_wmax[0], s_wmax[1]), fmaxf(s_wmax[2], s_wmax[3]));
        atomicMax(maxslot, __float_as_uint(bm));
    }
}

// ---------------------------------------------------------------------------
// Normalize: out *= 1/max
// ---------------------------------------------------------------------------
__global__ void normalize_kernel(float* __restrict__ out,
                                 const unsigned int* __restrict__ maxslot, int n4) {
    int i = blockIdx.x * blockDim.x + threadIdx.x;
    float inv = 1.0f / __uint_as_float(*maxslot);
    if (i < n4) {
        float4* o = (float4*)out;
        float4 vv = o[i];
        vv.x *= inv; vv.y *= inv; vv.z *= inv; vv.w *= inv;
        o[i] = vv;
    }
}

extern "C" void kernel_launch(void* const* d_in, const int* in_sizes, int n_in,
                              void* d_out, int out_size, void* d_ws, size_t ws_size,
                              hipStream_t stream) {
    const float* freqs = (const float*)d_in[0];
    const float* txp   = (const float*)d_in[1];
    const float* rxp   = (const float*)d_in[2];
    const float* xcrd  = (const float*)d_in[3];
    const float* ycrd  = (const float*)d_in[4];
    const float* zcrd  = (const float*)d_in[5];
    const float* yr    = (const float*)d_in[6];
    const float* yi    = (const float*)d_in[7];
    float* out = (float*)d_out;

    unsigned int* maxslot = (unsigned int*)d_ws;
    float* yt = (float*)((char*)d_ws + 256);
    const size_t need = 256 + (size_t)KTRN * 2 * sizeof(float);
    int use_yt = (ws_size >= need) ? 1 : 0;

    // prep: zero max slot + transpose y (32768 elements)
    prep_kernel<<<(KTRN + 255) / 256, 256, 0, stream>>>(yr, yi, yt, maxslot, use_yt);

    // main: 131072 voxels / 256 = 512 blocks
    kirchhoff_main<<<NVOX / 256, 256, 0, stream>>>(
        freqs, txp, rxp, xcrd, ycrd, zcrd, yt, yr, yi, out, maxslot, use_yt);

    // normalize: out_size/4 float4 elements
    int n4 = out_size / 4;
    normalize_kernel<<<(n4 + 255) / 256, 256, 0, stream>>>(out, maxslot, n4);
}

// Round 3
// 200.628 us; speedup vs baseline: 3.7332x; 3.7332x over previous
//
#include <hip/hip_runtime.h>
#include <math.h>

namespace {
constexpr int K = 16, T = 8, R = 8, NB = 32;
constexpr int NX = 64, NY = 64, NZ = 32;
constexpr int NVOX = NX * NY * NZ;                 // 131072
constexpr float TWO_PI_OVER_C = (float)(6.283185307179586 / 299792458.0);
constexpr float SCALE = 1.0f / 65536.0f;           // global scale on A; cancels in normalization
// B table: [tr(64)][out(2)][quad(4)][n(32)][j(8)] halves = 262144 B
constexpr int B_HALVES = 64 * 2 * 4 * 32 * 8;      // 131072
constexpr size_t WS_NEED = 256 + (size_t)B_HALVES * 2;
}

typedef _Float16 half8 __attribute__((ext_vector_type(8)));
typedef __fp16 fp16x2 __attribute__((ext_vector_type(2)));   // cvt_pkrtz native type
typedef float f32x4 __attribute__((ext_vector_type(4)));

// ---------------------------------------------------------------------------
// Prep: zero max slot; build B fragments in ws.
// B[k'][n] per (tr, out):  k'<16 -> (out0: yre, out1: yim),  k'>=16 -> (out0: -yim, out1: yre)
// Layout matches MFMA B-operand: lane reads [quad][n] row of 8 halves (16 B).
// ---------------------------------------------------------------------------
__global__ void prep_kernel(const float* __restrict__ yr, const float* __restrict__ yi,
                            _Float16* __restrict__ wsB, unsigned int* __restrict__ maxslot,
                            int use_ws) {
    int id = blockIdx.x * 256 + threadIdx.x;   // 16384 threads
    if (id == 0) *maxslot = 0u;
    if (!use_ws || id >= 64 * 2 * 4 * 32) return;
    int n    = id & 31;
    int quad = (id >> 5) & 3;
    int outc = (id >> 7) & 1;
    int tr   = id >> 8;
    int t = tr >> 3, r = tr & 7;
    bool second = quad >= 2;                    // k' >= 16 half (pairs with Aim)
    const float* src = (outc == 0) ? (second ? yi : yr) : (second ? yr : yi);
    float sg = (outc == 0 && second) ? -1.0f : 1.0f;
    int base = n * (K * T * R) + ((quad & 1) * 8) * (T * R) + t * R + r;
    half8 h;
#pragma unroll
    for (int j = 0; j < 8; ++j)
        h[j] = (_Float16)(sg * src[base + j * (T * R)]);
    ((half8*)wsB)[id] = h;
}

// ---------------------------------------------------------------------------
// Main: per wave, a 16-voxel x 32-batch complex output tile via MFMA.
// A generated in-register per lane (A[m=lane&15][k'=quad*8+j]), using
// (1+ikRt)(1+ikRr) separable form + phase rotation recurrence over freqs.
// ---------------------------------------------------------------------------
template <bool USE_WS>
__global__ __launch_bounds__(256) void kirch_mfma(
    const float* __restrict__ freqs,
    const float* __restrict__ txp, const float* __restrict__ rxp,
    const float* __restrict__ xc, const float* __restrict__ yc, const float* __restrict__ zc,
    const _Float16* __restrict__ wsB,
    const float* __restrict__ yr, const float* __restrict__ yi,
    float* __restrict__ out, unsigned int* __restrict__ maxslot)
{
    __shared__ float s_wmax[4];
    const int lane = threadIdx.x & 63;
    const int wave = threadIdx.x >> 6;
    const int nlo  = lane & 15;
    const int quad = lane >> 4;
    const int vb   = blockIdx.x * 64 + wave * 16;

    // A-gen voxel for this lane (fragment row m = lane&15)
    const int v = vb + nlo;
    const float px = xc[v >> 11];
    const float py = yc[(v >> 5) & 63];
    const float pz = zc[v & 31];

    const float k0 = TWO_PI_OVER_C * freqs[0];
    const float dk = TWO_PI_OVER_C * (freqs[K - 1] - freqs[0]) * (1.0f / (K - 1));

    const bool  isIm   = quad >= 2;
    const float kstart = k0 + ((quad & 1) ? 8.0f * dk : 0.0f);
    const float ks2    = kstart * kstart;
    const float ce     = dk * (2.0f * kstart + dk);   // for p recurrence
    const float de2c   = 2.0f * dk * dk;

    f32x4 accRe0 = {0,0,0,0}, accRe1 = {0,0,0,0};
    f32x4 accIm0 = {0,0,0,0}, accIm1 = {0,0,0,0};

    const char* bbase = (const char*)wsB + quad * 512 + nlo * 16;

    for (int t = 0; t < T; ++t) {
        const float txx = txp[t * 3 + 0], txy = txp[t * 3 + 1], txz = txp[t * 3 + 2];
        const float dxt = px - txx, dyt = py - txy, dzt = pz - txz;
        const float Rt = sqrtf(dxt * dxt + dyt * dyt + dzt * dzt);
        const float c4s = (4.0f * SCALE) * dzt;

        for (int r = 0; r < R; ++r) {
            const int tr = t * 8 + r;

            // ---- B fragments (issue loads early; L2-resident) ----
            half8 b00, b01, b10, b11;
            if (USE_WS) {
                const char* bp = bbase + tr * 4096;
                b00 = *(const half8*)(bp);             // Re-out, ntile 0
                b01 = *(const half8*)(bp + 256);       // Re-out, ntile 1
                b10 = *(const half8*)(bp + 2048);      // Im-out, ntile 0
                b11 = *(const half8*)(bp + 2304);      // Im-out, ntile 1
            } else {
                const int kb = (quad & 1) * 8;
                const float* sA = (quad < 2) ? yr : yi;          // Re-out source
                const float sgA = (quad < 2) ? 1.0f : -1.0f;
                const float* sB = (quad < 2) ? yi : yr;          // Im-out source
                auto gather = [&](const float* src, float sg, int n) {
                    int base = n * (K * T * R) + kb * (T * R) + tr;
                    half8 h;
#pragma unroll
                    for (int j = 0; j < 8; ++j) h[j] = (_Float16)(sg * src[base + j * (T * R)]);
                    return h;
                };
                b00 = gather(sA, sgA, nlo);
                b01 = gather(sA, sgA, 16 + nlo);
                b10 = gather(sB, 1.0f, nlo);
                b11 = gather(sB, 1.0f, 16 + nlo);
            }

            // ---- per-(t,r) geometry ----
            const float rxx = rxp[r * 3 + 0], rxy = rxp[r * 3 + 1], rxz = rxp[r * 3 + 2];
            const float dxr = px - rxx, dyr = py - rxy, dzr = pz - rxz;
            const float Rr = sqrtf(dxr * dxr + dyr * dyr + dzr * dzr);
            const float Rsum = Rt + Rr;
            const float Rprod = Rt * Rr;
            const float G = c4s * dzr;                       // = 4*S*dzt*dzr = S*g*Rprod
            const float g = G * __builtin_amdgcn_rcpf(Rprod);  // scaled g
            const float gRsum = g * Rsum;

            // ---- phase + polynomial recurrences over this lane's 8 freqs ----
            float c0, s0, cw, sw;
            __sincosf(kstart * Rsum, &s0, &c0);
            __sincosf(dk * Rsum, &sw, &cw);
            // Im-lanes: fold Im(z)=Re(-i z) into rotated start u' = (s0, -c0)
            float ur = isIm ? s0 : c0;
            float ui = isIm ? -c0 : s0;
            float q  = gRsum * kstart;
            const float dq = gRsum * dk;
            float p  = fmaf(-G, ks2, g);
            float e  = -G * ce;
            const float de = -de2c * G;

            float vals[8];
#pragma unroll
            for (int i = 0; i < 8; ++i) {
                vals[i] = fmaf(p, ur, -(q * ui));   // Re((p+iq)·u')
                if (i < 7) {
                    float nr = fmaf(ur, cw, -(ui * sw));
                    ui = fmaf(ur, sw, ui * cw);
                    ur = nr;
                    q += dq;
                    p += e;
                    e += de;
                }
            }

            union { half8 v8; fp16x2 v2[4]; } af;
#pragma unroll
            for (int i = 0; i < 4; ++i)
                af.v2[i] = __builtin_amdgcn_cvt_pkrtz(vals[2 * i], vals[2 * i + 1]);

            accRe0 = __builtin_amdgcn_mfma_f32_16x16x32_f16(af.v8, b00, accRe0, 0, 0, 0);
            accRe1 = __builtin_amdgcn_mfma_f32_16x16x32_f16(af.v8, b01, accRe1, 0, 0, 0);
            accIm0 = __builtin_amdgcn_mfma_f32_16x16x32_f16(af.v8, b10, accIm0, 0, 0, 0);
            accIm1 = __builtin_amdgcn_mfma_f32_16x16x32_f16(af.v8, b11, accIm1, 0, 0, 0);
        }
    }

    // ---- epilogue: magnitudes, store, block max ----
    // C/D layout: n = ntile*16 + (lane&15), m = quad*4 + reg
    float mx = 0.0f;
#pragma unroll
    for (int reg = 0; reg < 4; ++reg) {
        const int vv = vb + quad * 4 + reg;
        float re0 = accRe0[reg], im0 = accIm0[reg];
        float m0 = sqrtf(re0 * re0 + im0 * im0);
        out[nlo * NVOX + vv] = m0;
        float re1 = accRe1[reg], im1 = accIm1[reg];
        float m1 = sqrtf(re1 * re1 + im1 * im1);
        out[(16 + nlo) * NVOX + vv] = m1;
        mx = fmaxf(mx, fmaxf(m0, m1));
    }
#pragma unroll
    for (int off = 32; off > 0; off >>= 1)
        mx = fmaxf(mx, __shfl_down(mx, off));
    if (lane == 0) s_wmax[wave] = mx;
    __syncthreads();
    if (threadIdx.x == 0) {
        float bm = fmaxf(fmaxf(s_wmax[0], s_wmax[1]), fmaxf(s_wmax[2], s_wmax[3]));
        atomicMax(maxslot, __float_as_uint(bm));
    }
}

// ---------------------------------------------------------------------------
// Normalize: out *= 1/max
// ---------------------------------------------------------------------------
__global__ void normalize_kernel(float* __restrict__ out,
                                 const unsigned int* __restrict__ maxslot, int n4) {
    int i = blockIdx.x * blockDim.x + threadIdx.x;
    float inv = 1.0f / __uint_as_float(*maxslot);
    if (i < n4) {
        float4* o = (float4*)out;
        float4 vv = o[i];
        vv.x *= inv; vv.y *= inv; vv.z *= inv; vv.w *= inv;
        o[i] = vv;
    }
}

extern "C" void kernel_launch(void* const* d_in, const int* in_sizes, int n_in,
                              void* d_out, int out_size, void* d_ws, size_t ws_size,
                              hipStream_t stream) {
    const float* freqs = (const float*)d_in[0];
    const float* txp   = (const float*)d_in[1];
    const float* rxp   = (const float*)d_in[2];
    const float* xc    = (const float*)d_in[3];
    const float* yc    = (const float*)d_in[4];
    const float* zc    = (const float*)d_in[5];
    const float* yr    = (const float*)d_in[6];
    const float* yi    = (const float*)d_in[7];
    float* out = (float*)d_out;

    unsigned int* maxslot = (unsigned int*)d_ws;
    _Float16* wsB = (_Float16*)((char*)d_ws + 256);
    const int use_ws = (ws_size >= WS_NEED) ? 1 : 0;

    prep_kernel<<<64, 256, 0, stream>>>(yr, yi, wsB, maxslot, use_ws);

    if (use_ws)
        kirch_mfma<true><<<NVOX / 64, 256, 0, stream>>>(
            freqs, txp, rxp, xc, yc, zc, wsB, yr, yi, out, maxslot);
    else
        kirch_mfma<false><<<NVOX / 64, 256, 0, stream>>>(
            freqs, txp, rxp, xc, yc, zc, wsB, yr, yi, out, maxslot);

    int n4 = out_size / 4;
    normalize_kernel<<<(n4 + 255) / 256, 256, 0, stream>>>(out, maxslot, n4);
}

// Round 4
// 199.435 us; speedup vs baseline: 3.7555x; 1.0060x over previous
//
#include <hip/hip_runtime.h>
#include <math.h>

namespace {
constexpr int K = 16, T = 8, R = 8, NB = 32;
constexpr int NX = 64, NY = 64, NZ = 32;
constexpr int NVOX = NX * NY * NZ;                 // 131072
constexpr float TWO_PI_OVER_C = (float)(6.283185307179586 / 299792458.0);
constexpr float CT_SCALE = 4.0f / 256.0f;          // folded 4 and 1/65536 split across Ht,Hr
constexpr float CR_SCALE = 1.0f / 256.0f;          // total scale = 4/65536; cancels in normalize
// B table: [tr(64)][out(2)][quad(4)][n(32)][j(8)] halves = 262144 B
constexpr int B_HALVES = 64 * 2 * 4 * 32 * 8;      // 131072
constexpr size_t WS_NEED = 256 + (size_t)B_HALVES * 2;
}

typedef _Float16 half8 __attribute__((ext_vector_type(8)));
typedef __fp16 fp16x2 __attribute__((ext_vector_type(2)));   // cvt_pkrtz native type
typedef float f32x4 __attribute__((ext_vector_type(4)));

// ---------------------------------------------------------------------------
// Prep: zero max slot; build B fragments in ws.
// B[k'][n] per (tr, out):  k'<16 -> (out0: yre, out1: yim),  k'>=16 -> (out0: -yim, out1: yre)
// ---------------------------------------------------------------------------
__global__ void prep_kernel(const float* __restrict__ yr, const float* __restrict__ yi,
                            _Float16* __restrict__ wsB, unsigned int* __restrict__ maxslot,
                            int use_ws) {
    int id = blockIdx.x * 256 + threadIdx.x;   // 16384 threads
    if (id == 0) *maxslot = 0u;
    if (!use_ws || id >= 64 * 2 * 4 * 32) return;
    int n    = id & 31;
    int quad = (id >> 5) & 3;
    int outc = (id >> 7) & 1;
    int tr   = id >> 8;
    int t = tr >> 3, r = tr & 7;
    bool second = quad >= 2;                    // k' >= 16 half (pairs with AIm)
    const float* src = (outc == 0) ? (second ? yi : yr) : (second ? yr : yi);
    float sg = (outc == 0 && second) ? -1.0f : 1.0f;
    int base = n * (K * T * R) + ((quad & 1) * 8) * (T * R) + t * R + r;
    half8 h;
#pragma unroll
    for (int j = 0; j < 8; ++j)
        h[j] = (_Float16)(sg * src[base + j * (T * R)]);
    ((half8*)wsB)[id] = h;
}

// ---------------------------------------------------------------------------
// Main: per wave, 16-voxel x 32-batch complex tile via MFMA.
// A = 4*Ht*Hr factorization: Hr table in LDS (built once per block),
// Ht in registers per t (8-freq recurrence), inner loop = packed-fp16
// complex product + 4 MFMAs.
// ---------------------------------------------------------------------------
template <bool USE_WS>
__global__ __launch_bounds__(256, 4) void kirch_mfma(
    const float* __restrict__ freqs,
    const float* __restrict__ txp, const float* __restrict__ rxp,
    const float* __restrict__ xc, const float* __restrict__ yc, const float* __restrict__ zc,
    const _Float16* __restrict__ wsB,
    const float* __restrict__ yr, const float* __restrict__ yi,
    float* __restrict__ out, unsigned int* __restrict__ maxslot)
{
    __shared__ _Float16 sHrRe[8][2][64][8];   // [r][kh][vox][j]  16 KB
    __shared__ _Float16 sHrIm[8][2][64][8];   // 16 KB
    __shared__ float s_wmax[4];

    const int tid  = threadIdx.x;
    const int lane = tid & 63;
    const int wave = tid >> 6;
    const int nlo  = lane & 15;
    const int quad = lane >> 4;
    const int kh   = quad & 1;
    const int vb   = blockIdx.x * 64 + wave * 16;
    const int v    = vb + nlo;                 // this lane's voxel (fragment row m)
    const int bv2  = wave * 16 + nlo;          // block-local voxel index

    const float k0 = TWO_PI_OVER_C * freqs[0];
    const float dk = TWO_PI_OVER_C * (freqs[K - 1] - freqs[0]) * (1.0f / (K - 1));

    // ---- Phase 1: cooperatively build Hr table (64 vox x 8 r x 16 k) ----
#pragma unroll
    for (int s = 0; s < 2; ++s) {
        int task = tid + (s << 8);             // 512 tasks
        int bv = task & 63;
        int r  = task >> 6;
        int gv = blockIdx.x * 64 + bv;
        float qx = xc[gv >> 11];
        float qy = yc[(gv >> 5) & 63];
        float qz = zc[gv & 31];
        float rxx = rxp[r * 3 + 0], rxy = rxp[r * 3 + 1], rxz = rxp[r * 3 + 2];
        float dx = qx - rxx, dy = qy - rxy, dz = qz - rxz;
        float Rr = sqrtf(dx * dx + dy * dy + dz * dz);
        float c = CR_SCALE * dz * __builtin_amdgcn_rcpf(Rr);
        float sph, cph, swp, cwp;
        __sincosf(k0 * Rr, &sph, &cph);
        __sincosf(dk * Rr, &swp, &cwp);
        float ur = cph, ui = sph;
        float ck = c * (k0 * Rr);
        const float dck = c * (dk * Rr);
        float re[16], im[16];
#pragma unroll
        for (int kk = 0; kk < 16; ++kk) {
            re[kk] = fmaf(c, ur, -(ck * ui));   // c*(ur - kR*ui)
            im[kk] = fmaf(c, ui,  (ck * ur));   // c*(ui + kR*ur)
            float nr = fmaf(ur, cwp, -(ui * swp));
            ui = fmaf(ur, swp, ui * cwp);
            ur = nr;
            ck += dck;
        }
        union { half8 v8; fp16x2 v2[4]; } h;
#pragma unroll
        for (int kk2 = 0; kk2 < 2; ++kk2) {
#pragma unroll
            for (int i = 0; i < 4; ++i)
                h.v2[i] = __builtin_amdgcn_cvt_pkrtz(re[kk2 * 8 + 2 * i], re[kk2 * 8 + 2 * i + 1]);
            *(half8*)&sHrRe[r][kk2][bv][0] = h.v8;
#pragma unroll
            for (int i = 0; i < 4; ++i)
                h.v2[i] = __builtin_amdgcn_cvt_pkrtz(im[kk2 * 8 + 2 * i], im[kk2 * 8 + 2 * i + 1]);
            *(half8*)&sHrIm[r][kk2][bv][0] = h.v8;
        }
    }
    __syncthreads();

    // ---- per-lane constants for phase 2 ----
    const float px = xc[v >> 11];
    const float py = yc[(v >> 5) & 63];
    const float pz = zc[v & 31];
    const float kstart = k0 + (kh ? 8.0f * dk : 0.0f);

    // X/Y plane selection: Re-quads compute ARe = HtRe*HrRe - HtIm*HrIm
    //                      Im-quads compute AIm = HtRe*HrIm + HtIm*HrRe
    // A = HtRe*X + HtIm*Y with X = sel(HrRe,HrIm), Y = sel(-HrIm,HrRe)
    const _Float16* pX = (quad < 2) ? &sHrRe[0][kh][bv2][0] : &sHrIm[0][kh][bv2][0];
    const _Float16* pZ = (quad < 2) ? &sHrIm[0][kh][bv2][0] : &sHrRe[0][kh][bv2][0];
    const unsigned int sgn = (quad < 2) ? 0x80008000u : 0u;

    f32x4 accRe0 = {0,0,0,0}, accRe1 = {0,0,0,0};
    f32x4 accIm0 = {0,0,0,0}, accIm1 = {0,0,0,0};

    const char* bbase = (const char*)wsB + quad * 512 + nlo * 16;

    for (int t = 0; t < T; ++t) {
        // ---- Ht for this (voxel, t) over the lane's 8 freqs, in registers ----
        const float txx = txp[t * 3 + 0], txy = txp[t * 3 + 1], txz = txp[t * 3 + 2];
        const float dxt = px - txx, dyt = py - txy, dzt = pz - txz;
        const float Rt = sqrtf(dxt * dxt + dyt * dyt + dzt * dzt);
        const float c = CT_SCALE * dzt * __builtin_amdgcn_rcpf(Rt);
        float sph, cph, swp, cwp;
        __sincosf(kstart * Rt, &sph, &cph);
        __sincosf(dk * Rt, &swp, &cwp);
        float ur = cph, ui = sph;
        float ck = c * (kstart * Rt);
        const float dck = c * (dk * Rt);
        float hre[8], him[8];
#pragma unroll
        for (int j = 0; j < 8; ++j) {
            hre[j] = fmaf(c, ur, -(ck * ui));
            him[j] = fmaf(c, ui,  (ck * ur));
            if (j < 7) {
                float nr = fmaf(ur, cwp, -(ui * swp));
                ui = fmaf(ur, swp, ui * cwp);
                ur = nr;
                ck += dck;
            }
        }
        union { half8 v8; fp16x2 v2[4]; } HtRe, HtIm;
#pragma unroll
        for (int i = 0; i < 4; ++i) {
            HtRe.v2[i] = __builtin_amdgcn_cvt_pkrtz(hre[2 * i], hre[2 * i + 1]);
            HtIm.v2[i] = __builtin_amdgcn_cvt_pkrtz(him[2 * i], him[2 * i + 1]);
        }

#pragma unroll
        for (int r = 0; r < R; ++r) {
            const int tr = t * 8 + r;

            // ---- B fragments (L2-resident) ----
            half8 b00, b01, b10, b11;
            if (USE_WS) {
                const char* bp = bbase + tr * 4096;
                b00 = *(const half8*)(bp);             // Re-out, ntile 0
                b01 = *(const half8*)(bp + 256);       // Re-out, ntile 1
                b10 = *(const half8*)(bp + 2048);      // Im-out, ntile 0
                b11 = *(const half8*)(bp + 2304);      // Im-out, ntile 1
            } else {
                const int kb = kh * 8;
                const float* sA = (quad < 2) ? yr : yi;
                const float sgA = (quad < 2) ? 1.0f : -1.0f;
                const float* sB = (quad < 2) ? yi : yr;
                auto gather = [&](const float* src, float sg, int n) {
                    int base = n * (K * T * R) + kb * (T * R) + tr;
                    half8 h;
#pragma unroll
                    for (int j = 0; j < 8; ++j) h[j] = (_Float16)(sg * src[base + j * (T * R)]);
                    return h;
                };
                b00 = gather(sA, sgA, nlo);
                b01 = gather(sA, sgA, 16 + nlo);
                b10 = gather(sB, 1.0f, nlo);
                b11 = gather(sB, 1.0f, 16 + nlo);
            }

            // ---- A fragment: packed-fp16 complex product ----
            half8 X = *(const half8*)(pX + r * 1024);
            union { half8 h; unsigned int u[4]; } Z, Y;
            Z.h = *(const half8*)(pZ + r * 1024);
#pragma unroll
            for (int i = 0; i < 4; ++i) Y.u[i] = Z.u[i] ^ sgn;
            half8 A8 = HtRe.v8 * X + HtIm.v8 * Y.h;    // v_pk_mul/v_pk_fma

            accRe0 = __builtin_amdgcn_mfma_f32_16x16x32_f16(A8, b00, accRe0, 0, 0, 0);
            accRe1 = __builtin_amdgcn_mfma_f32_16x16x32_f16(A8, b01, accRe1, 0, 0, 0);
            accIm0 = __builtin_amdgcn_mfma_f32_16x16x32_f16(A8, b10, accIm0, 0, 0, 0);
            accIm1 = __builtin_amdgcn_mfma_f32_16x16x32_f16(A8, b11, accIm1, 0, 0, 0);
        }
    }

    // ---- epilogue: magnitudes, store, block max ----
    // C/D layout: n = ntile*16 + (lane&15), m = quad*4 + reg
    float mx = 0.0f;
#pragma unroll
    for (int reg = 0; reg < 4; ++reg) {
        const int vv = vb + quad * 4 + reg;
        float re0 = accRe0[reg], im0 = accIm0[reg];
        float m0 = sqrtf(re0 * re0 + im0 * im0);
        out[nlo * NVOX + vv] = m0;
        float re1 = accRe1[reg], im1 = accIm1[reg];
        float m1 = sqrtf(re1 * re1 + im1 * im1);
        out[(16 + nlo) * NVOX + vv] = m1;
        mx = fmaxf(mx, fmaxf(m0, m1));
    }
#pragma unroll
    for (int off = 32; off > 0; off >>= 1)
        mx = fmaxf(mx, __shfl_down(mx, off));
    if (lane == 0) s_wmax[wave] = mx;
    __syncthreads();
    if (threadIdx.x == 0) {
        float bm = fmaxf(fmaxf(s_wmax[0], s_wmax[1]), fmaxf(s_wmax[2], s_wmax[3]));
        atomicMax(maxslot, __float_as_uint(bm));
    }
}

// ---------------------------------------------------------------------------
// Normalize: out *= 1/max
// ---------------------------------------------------------------------------
__global__ void normalize_kernel(float* __restrict__ out,
                                 const unsigned int* __restrict__ maxslot, int n4) {
    int i = blockIdx.x * blockDim.x + threadIdx.x;
    float inv = 1.0f / __uint_as_float(*maxslot);
    if (i < n4) {
        float4* o = (float4*)out;
        float4 vv = o[i];
        vv.x *= inv; vv.y *= inv; vv.z *= inv; vv.w *= inv;
        o[i] = vv;
    }
}

extern "C" void kernel_launch(void* const* d_in, const int* in_sizes, int n_in,
                              void* d_out, int out_size, void* d_ws, size_t ws_size,
                              hipStream_t stream) {
    const float* freqs = (const float*)d_in[0];
    const float* txp   = (const float*)d_in[1];
    const float* rxp   = (const float*)d_in[2];
    const float* xc    = (const float*)d_in[3];
    const float* yc    = (const float*)d_in[4];
    const float* zc    = (const float*)d_in[5];
    const float* yr    = (const float*)d_in[6];
    const float* yi    = (const float*)d_in[7];
    float* out = (float*)d_out;

    unsigned int* maxslot = (unsigned int*)d_ws;
    _Float16* wsB = (_Float16*)((char*)d_ws + 256);
    const int use_ws = (ws_size >= WS_NEED) ? 1 : 0;

    prep_kernel<<<64, 256, 0, stream>>>(yr, yi, wsB, maxslot, use_ws);

    if (use_ws)
        kirch_mfma<true><<<NVOX / 64, 256, 0, stream>>>(
            freqs, txp, rxp, xc, yc, zc, wsB, yr, yi, out, maxslot);
    else
        kirch_mfma<false><<<NVOX / 64, 256, 0, stream>>>(
            freqs, txp, rxp, xc, yc, zc, wsB, yr, yi, out, maxslot);

    int n4 = out_size / 4;
    normalize_kernel<<<(n4 + 255) / 256, 256, 0, stream>>>(out, maxslot, n4);
}